// Round 1
// baseline (87.315 us; speedup 1.0000x reference)
//
#include <hip/hip_runtime.h>

#define Q_MIN 0.5f
#define S_B_C 1.0f
#define MAXK 512
#define BLK 256
#define MAXB 1024

struct Scratch {
  unsigned long long packed[MAXK];   // (q_bits << 32) | (0xFFFFFFFF - idx): atomicMax == (max q, min idx)
  unsigned int fcbits[MAXK];         // float-as-uint atomicMax for segment_max (f > 0)
  unsigned int n_bkg;
  unsigned int _pad;
  float4 a0[MAXK];                   // 2*x_a[0..3]
  float4 a1[MAXK];                   // 2*x_a[4..7]
  float2 uq[MAXK];                   // (1 - ||x_a||^2, q_ak)
  float fcenter[MAXK];
  float partial_lv[MAXB];
  float partial_bkg[MAXB];
};

__device__ __forceinline__ float qfun(float fv) {
  float a = atanhf(fv);
  return fmaf(a, a, Q_MIN);
}

__global__ void k_init(Scratch* ws) {
  int t = blockIdx.x * blockDim.x + threadIdx.x;
  if (t < MAXK) { ws->packed[t] = 0ull; ws->fcbits[t] = 0u; }
  if (t == 0) { ws->n_bkg = 0u; }
}

__global__ void k_argmax(const float* __restrict__ f, const int* __restrict__ y,
                         int n, Scratch* __restrict__ ws) {
  int i = blockIdx.x * blockDim.x + threadIdx.x;
  if (i >= n) return;
  int yi = y[i];
  if (yi >= 0 && yi < MAXK) {
    float q = qfun(f[i]);
    unsigned long long p = ((unsigned long long)__float_as_uint(q) << 32)
                         | (unsigned long long)(0xFFFFFFFFu - (unsigned)i);
    atomicMax(&ws->packed[yi], p);
  }
}

__global__ void k_edges(const float* __restrict__ f, const int* __restrict__ ei,
                        const int* __restrict__ ej, int e, Scratch* __restrict__ ws) {
  int t = blockIdx.x * blockDim.x + threadIdx.x;
  if (t >= e) return;
  int j = ej[t];
  if (j >= 0 && j < MAXK)
    atomicMax(&ws->fcbits[j], __float_as_uint(f[ei[t]]));
}

__global__ void k_centers(const float* __restrict__ x, const int* __restrict__ kptr,
                          Scratch* __restrict__ ws) {
  int K = kptr[0]; if (K > MAXK) K = MAXK;
  int t = blockIdx.x * blockDim.x + threadIdx.x;
  if (t >= MAXK) return;
  float4 a0 = make_float4(0.f, 0.f, 0.f, 0.f);
  float4 a1 = make_float4(0.f, 0.f, 0.f, 0.f);
  float u = 0.f, q = 0.f, fc = 0.f;
  if (t < K) {
    unsigned long long p = ws->packed[t];
    q = __uint_as_float((unsigned)(p >> 32));
    unsigned idx = 0xFFFFFFFFu - (unsigned)(p & 0xFFFFFFFFull);
    const float4* xp = (const float4*)(x + (size_t)idx * 8);
    float4 v0 = xp[0], v1 = xp[1];
    float s2 = v0.x*v0.x + v0.y*v0.y + v0.z*v0.z + v0.w*v0.w
             + v1.x*v1.x + v1.y*v1.y + v1.z*v1.z + v1.w*v1.w;
    u = 1.f - s2;
    a0 = make_float4(2.f*v0.x, 2.f*v0.y, 2.f*v0.z, 2.f*v0.w);
    a1 = make_float4(2.f*v1.x, 2.f*v1.y, 2.f*v1.z, 2.f*v1.w);
    fc = __uint_as_float(ws->fcbits[t]);  // init 0 => already max(.,0)
  }
  ws->a0[t] = a0;
  ws->a1[t] = a1;
  ws->uq[t] = make_float2(u, q);
  ws->fcenter[t] = fc;
}

__global__ void __launch_bounds__(BLK) k_main(const float* __restrict__ x,
    const float* __restrict__ f, const int* __restrict__ y, int n,
    Scratch* __restrict__ ws) {
  __shared__ float4 sA0[MAXK];
  __shared__ float4 sA1[MAXK];
  __shared__ float2 sUQ[MAXK];
  for (int t = threadIdx.x; t < MAXK; t += BLK) {
    sA0[t] = ws->a0[t];
    sA1[t] = ws->a1[t];
    sUQ[t] = ws->uq[t];
  }
  __syncthreads();

  float lv = 0.f, bk = 0.f;
  int cnt = 0;
  int stride = gridDim.x * BLK;
  for (int i = blockIdx.x * BLK + threadIdx.x; i < n; i += stride) {
    const float4* xp = (const float4*)(x + (size_t)i * 8);
    float4 p0 = xp[0], p1 = xp[1];
    float x2i = p0.x*p0.x + p0.y*p0.y + p0.z*p0.z + p0.w*p0.w
              + p1.x*p1.x + p1.y*p1.y + p1.z*p1.z + p1.w*p1.w;
    int yi = y[i];
    float fi = f[i];
    float qi = qfun(fi);
    float negx2 = -x2i;
    float acc = 0.f;
    #pragma unroll 8
    for (int k = 0; k < MAXK; ++k) {
      float4 a0 = sA0[k], a1 = sA1[k];
      float2 uq = sUQ[k];
      float r = uq.x + negx2;
      r = fmaf(p0.x, a0.x, r); r = fmaf(p0.y, a0.y, r);
      r = fmaf(p0.z, a0.z, r); r = fmaf(p0.w, a0.w, r);
      r = fmaf(p1.x, a1.x, r); r = fmaf(p1.y, a1.y, r);
      r = fmaf(p1.z, a1.z, r); r = fmaf(p1.w, a1.w, r);
      float xinv = __builtin_amdgcn_fmed3f(r, 0.f, 1.f);   // clamp(r,0,1)
      acc = fmaf(xinv, uq.y, acc);
    }
    if (yi >= 0) {
      // fixup: replace the xinv term for k==yi by the member term x_diff
      float4 a0 = sA0[yi], a1 = sA1[yi];
      float2 uq = sUQ[yi];
      float r = uq.x + negx2;
      r = fmaf(p0.x, a0.x, r); r = fmaf(p0.y, a0.y, r);
      r = fmaf(p0.z, a0.z, r); r = fmaf(p0.w, a0.w, r);
      r = fmaf(p1.x, a1.x, r); r = fmaf(p1.y, a1.y, r);
      r = fmaf(p1.z, a1.z, r); r = fmaf(p1.w, a1.w, r);
      float xinv = __builtin_amdgcn_fmed3f(r, 0.f, 1.f);
      float xd = fmaxf(1.f - r, 0.f);                      // x_diff clamped at 0
      acc = fmaf(xd - xinv, uq.y, acc);
    } else {
      bk += fi;
      cnt += 1;
    }
    lv = fmaf(acc, qi, lv);
  }

  // deterministic reductions: wave shuffle tree + fixed-order cross-wave
  for (int o = 32; o > 0; o >>= 1) {
    lv += __shfl_down(lv, o, 64);
    bk += __shfl_down(bk, o, 64);
    cnt += __shfl_down(cnt, o, 64);
  }
  __shared__ float rlv[BLK / 64], rbk[BLK / 64];
  __shared__ int rcnt[BLK / 64];
  int wid = threadIdx.x >> 6;
  int lane = threadIdx.x & 63;
  if (lane == 0) { rlv[wid] = lv; rbk[wid] = bk; rcnt[wid] = cnt; }
  __syncthreads();
  if (threadIdx.x == 0) {
    float slv = 0.f, sbk = 0.f; int sc = 0;
    #pragma unroll
    for (int w = 0; w < BLK / 64; ++w) { slv += rlv[w]; sbk += rbk[w]; sc += rcnt[w]; }
    ws->partial_lv[blockIdx.x] = slv;
    ws->partial_bkg[blockIdx.x] = sbk;
    if (sc) atomicAdd(&ws->n_bkg, (unsigned)sc);
  }
}

__global__ void __launch_bounds__(BLK) k_final(const int* __restrict__ kptr, int n, int nb,
    const Scratch* __restrict__ ws, float* __restrict__ out) {
  int K = kptr[0]; if (K > MAXK) K = MAXK;
  int tid = threadIdx.x;
  float a = 0.f, b = 0.f, c = 0.f;
  for (int t = tid; t < nb; t += BLK) { a += ws->partial_lv[t]; b += ws->partial_bkg[t]; }
  for (int t = tid; t < K; t += BLK) c += ws->fcenter[t];
  __shared__ float sa[BLK], sb[BLK], sc[BLK];
  sa[tid] = a; sb[tid] = b; sc[tid] = c;
  __syncthreads();
  for (int o = BLK / 2; o > 0; o >>= 1) {
    if (tid < o) { sa[tid] += sa[tid + o]; sb[tid] += sb[tid + o]; sc[tid] += sc[tid + o]; }
    __syncthreads();
  }
  if (tid == 0) {
    float b1 = 1.f - sc[0] / (float)K;
    float b2 = S_B_C / (float)ws->n_bkg * sb[0];
    out[0] = (b1 + b2) + sa[0] / (float)n;
  }
}

extern "C" void kernel_launch(void* const* d_in, const int* in_sizes, int n_in,
                              void* d_out, int out_size, void* d_ws, size_t ws_size,
                              hipStream_t stream) {
  const float* x = (const float*)d_in[0];
  const float* f = (const float*)d_in[1];
  const int*   y = (const int*)d_in[2];
  const int*  ei = (const int*)d_in[3];
  const int*  ej = (const int*)d_in[4];
  const int* kptr = (const int*)d_in[5];
  float* out = (float*)d_out;
  int n = in_sizes[1];
  int e = in_sizes[3];
  Scratch* ws = (Scratch*)d_ws;

  int nb = (n + BLK - 1) / BLK;
  if (nb > MAXB) nb = MAXB;   // k_main grid-strides if capped

  hipLaunchKernelGGL(k_init,   dim3((MAXK + BLK - 1) / BLK), dim3(BLK), 0, stream, ws);
  hipLaunchKernelGGL(k_argmax, dim3((n + BLK - 1) / BLK),    dim3(BLK), 0, stream, f, y, n, ws);
  hipLaunchKernelGGL(k_edges,  dim3((e + BLK - 1) / BLK),    dim3(BLK), 0, stream, f, ei, ej, e, ws);
  hipLaunchKernelGGL(k_centers, dim3(MAXK / BLK),            dim3(BLK), 0, stream, x, kptr, ws);
  hipLaunchKernelGGL(k_main,   dim3(nb),                     dim3(BLK), 0, stream, x, f, y, n, ws);
  hipLaunchKernelGGL(k_final,  dim3(1),                      dim3(BLK), 0, stream, kptr, n, nb, ws, out);
}

// Round 2
// 86.201 us; speedup vs baseline: 1.0129x; 1.0129x over previous
//
#include <hip/hip_runtime.h>

#define Q_MIN 0.5f
#define S_B_C 1.0f
#define MAXK 512
#define BLK 256
#define MAXB 1024

struct Scratch {
  unsigned long long packed[MAXK];   // (q_bits << 32) | (0xFFFFFFFF - idx): atomicMax == (max q, min idx)
  unsigned int fcbits[MAXK];         // float-as-uint atomicMax for segment_max (f > 0)
  unsigned int n_bkg;
  unsigned int _pad[3];
  float4 ab[MAXK * 2];               // ab[2k] = 2*x_a[0..3], ab[2k+1] = 2*x_a[4..7]
  float2 uq[MAXK];                   // (1 - ||x_a||^2, q_ak)
  float partial_lv[MAXB];
  float partial_bkg[MAXB];
};

__device__ __forceinline__ float qfun(float fv) {
  float a = atanhf(fv);
  return fmaf(a, a, Q_MIN);
}

__global__ void k_init(Scratch* ws) {
  int t = blockIdx.x * blockDim.x + threadIdx.x;
  if (t < MAXK) { ws->packed[t] = 0ull; ws->fcbits[t] = 0u; }
  if (t == 0) { ws->n_bkg = 0u; }
}

// fused: per-hit q-argmax scatter + edge segment-max scatter
__global__ void k_scatter(const float* __restrict__ f, const int* __restrict__ y,
                          const int* __restrict__ ei, const int* __restrict__ ej,
                          int n, int e, Scratch* __restrict__ ws) {
  int t = blockIdx.x * blockDim.x + threadIdx.x;
  if (t < n) {
    int yi = y[t];
    if (yi >= 0 && yi < MAXK) {
      float q = qfun(f[t]);
      unsigned long long p = ((unsigned long long)__float_as_uint(q) << 32)
                           | (unsigned long long)(0xFFFFFFFFu - (unsigned)t);
      atomicMax(&ws->packed[yi], p);
    }
  }
  if (t < e) {
    int j = ej[t];
    if (j >= 0 && j < MAXK)
      atomicMax(&ws->fcbits[j], __float_as_uint(f[ei[t]]));
  }
}

__global__ void k_centers(const float* __restrict__ x, const int* __restrict__ kptr,
                          Scratch* __restrict__ ws) {
  int K = kptr[0]; if (K > MAXK) K = MAXK;
  int t = blockIdx.x * blockDim.x + threadIdx.x;
  if (t >= MAXK) return;
  float4 a0 = make_float4(0.f, 0.f, 0.f, 0.f);
  float4 a1 = make_float4(0.f, 0.f, 0.f, 0.f);
  float u = 0.f, q = 0.f;
  if (t < K) {
    unsigned long long p = ws->packed[t];
    q = __uint_as_float((unsigned)(p >> 32));
    unsigned idx = 0xFFFFFFFFu - (unsigned)(p & 0xFFFFFFFFull);
    const float4* xp = (const float4*)(x + (size_t)idx * 8);
    float4 v0 = xp[0], v1 = xp[1];
    float s2 = v0.x*v0.x + v0.y*v0.y + v0.z*v0.z + v0.w*v0.w
             + v1.x*v1.x + v1.y*v1.y + v1.z*v1.z + v1.w*v1.w;
    u = 1.f - s2;
    a0 = make_float4(2.f*v0.x, 2.f*v0.y, 2.f*v0.z, 2.f*v0.w);
    a1 = make_float4(2.f*v1.x, 2.f*v1.y, 2.f*v1.z, 2.f*v1.w);
  }
  ws->ab[2 * t]     = a0;
  ws->ab[2 * t + 1] = a1;
  ws->uq[t] = make_float2(u, q);
}

__global__ void __launch_bounds__(BLK) k_main(const float* __restrict__ x,
    const float* __restrict__ f, const int* __restrict__ y, int n,
    Scratch* __restrict__ ws) {
  // per-k table is read with wave-uniform indices -> compiler emits s_load
  // (scalar pipe), freeing LDS/vector-mem entirely.
  const float4* __restrict__ tab = ws->ab;
  const float2* __restrict__ uqt = ws->uq;

  float lv = 0.f, bk = 0.f;
  int cnt = 0;
  int stride = gridDim.x * BLK;
  for (int i = blockIdx.x * BLK + threadIdx.x; i < n; i += stride) {
    const float4* xp = (const float4*)(x + (size_t)i * 8);
    float4 p0 = xp[0], p1 = xp[1];
    float x2i = p0.x*p0.x + p0.y*p0.y + p0.z*p0.z + p0.w*p0.w
              + p1.x*p1.x + p1.y*p1.y + p1.z*p1.z + p1.w*p1.w;
    int yi = y[i];
    float fi = f[i];
    float qi = qfun(fi);
    float negx2 = -x2i;
    float acc = 0.f;
    #pragma unroll 8
    for (int k = 0; k < MAXK; ++k) {
      float4 a0 = tab[2 * k];
      float4 a1 = tab[2 * k + 1];
      float2 uq = uqt[k];
      float r = uq.x + negx2;
      r = fmaf(p0.x, a0.x, r); r = fmaf(p0.y, a0.y, r);
      r = fmaf(p0.z, a0.z, r); r = fmaf(p0.w, a0.w, r);
      r = fmaf(p1.x, a1.x, r); r = fmaf(p1.y, a1.y, r);
      r = fmaf(p1.z, a1.z, r); r = fmaf(p1.w, a1.w, r);
      float xinv = __builtin_amdgcn_fmed3f(r, 0.f, 1.f);   // clamp(r,0,1)
      acc = fmaf(xinv, uq.y, acc);
    }
    if (yi >= 0) {
      // fixup: replace the xinv term for k==yi by the member term x_diff
      float4 a0 = tab[2 * yi];       // divergent gather, 20KB table L1/L2-hot
      float4 a1 = tab[2 * yi + 1];
      float2 uq = uqt[yi];
      float r = uq.x + negx2;
      r = fmaf(p0.x, a0.x, r); r = fmaf(p0.y, a0.y, r);
      r = fmaf(p0.z, a0.z, r); r = fmaf(p0.w, a0.w, r);
      r = fmaf(p1.x, a1.x, r); r = fmaf(p1.y, a1.y, r);
      r = fmaf(p1.z, a1.z, r); r = fmaf(p1.w, a1.w, r);
      float xinv = __builtin_amdgcn_fmed3f(r, 0.f, 1.f);
      float xd = fmaxf(1.f - r, 0.f);                      // x_diff clamped at 0
      acc = fmaf(xd - xinv, uq.y, acc);
    } else {
      bk += fi;
      cnt += 1;
    }
    lv = fmaf(acc, qi, lv);
  }

  // deterministic reductions: wave shuffle tree + fixed-order cross-wave
  for (int o = 32; o > 0; o >>= 1) {
    lv += __shfl_down(lv, o, 64);
    bk += __shfl_down(bk, o, 64);
    cnt += __shfl_down(cnt, o, 64);
  }
  __shared__ float rlv[BLK / 64], rbk[BLK / 64];
  __shared__ int rcnt[BLK / 64];
  int wid = threadIdx.x >> 6;
  int lane = threadIdx.x & 63;
  if (lane == 0) { rlv[wid] = lv; rbk[wid] = bk; rcnt[wid] = cnt; }
  __syncthreads();
  if (threadIdx.x == 0) {
    float slv = 0.f, sbk = 0.f; int sc = 0;
    #pragma unroll
    for (int w = 0; w < BLK / 64; ++w) { slv += rlv[w]; sbk += rbk[w]; sc += rcnt[w]; }
    ws->partial_lv[blockIdx.x] = slv;
    ws->partial_bkg[blockIdx.x] = sbk;
    if (sc) atomicAdd(&ws->n_bkg, (unsigned)sc);
  }
}

__global__ void __launch_bounds__(BLK) k_final(const int* __restrict__ kptr, int n, int nb,
    const Scratch* __restrict__ ws, float* __restrict__ out) {
  int K = kptr[0]; if (K > MAXK) K = MAXK;
  int tid = threadIdx.x;
  float a = 0.f, b = 0.f, c = 0.f;
  for (int t = tid; t < nb; t += BLK) { a += ws->partial_lv[t]; b += ws->partial_bkg[t]; }
  for (int t = tid; t < MAXK; t += BLK) c += __uint_as_float(ws->fcbits[t]); // 0 for t>=K
  __shared__ float sa[BLK], sb[BLK], sc[BLK];
  sa[tid] = a; sb[tid] = b; sc[tid] = c;
  __syncthreads();
  for (int o = BLK / 2; o > 0; o >>= 1) {
    if (tid < o) { sa[tid] += sa[tid + o]; sb[tid] += sb[tid + o]; sc[tid] += sc[tid + o]; }
    __syncthreads();
  }
  if (tid == 0) {
    float b1 = 1.f - sc[0] / (float)K;
    float b2 = S_B_C / (float)ws->n_bkg * sb[0];
    out[0] = (b1 + b2) + sa[0] / (float)n;
  }
}

extern "C" void kernel_launch(void* const* d_in, const int* in_sizes, int n_in,
                              void* d_out, int out_size, void* d_ws, size_t ws_size,
                              hipStream_t stream) {
  const float* x = (const float*)d_in[0];
  const float* f = (const float*)d_in[1];
  const int*   y = (const int*)d_in[2];
  const int*  ei = (const int*)d_in[3];
  const int*  ej = (const int*)d_in[4];
  const int* kptr = (const int*)d_in[5];
  float* out = (float*)d_out;
  int n = in_sizes[1];
  int e = in_sizes[3];
  Scratch* ws = (Scratch*)d_ws;

  int nb = (n + BLK - 1) / BLK;
  if (nb > MAXB) nb = MAXB;   // k_main grid-strides if capped
  int nmax = n > e ? n : e;

  hipLaunchKernelGGL(k_init,    dim3((MAXK + BLK - 1) / BLK), dim3(BLK), 0, stream, ws);
  hipLaunchKernelGGL(k_scatter, dim3((nmax + BLK - 1) / BLK), dim3(BLK), 0, stream,
                     f, y, ei, ej, n, e, ws);
  hipLaunchKernelGGL(k_centers, dim3(MAXK / BLK),             dim3(BLK), 0, stream, x, kptr, ws);
  hipLaunchKernelGGL(k_main,    dim3(nb),                     dim3(BLK), 0, stream, x, f, y, n, ws);
  hipLaunchKernelGGL(k_final,   dim3(1),                      dim3(BLK), 0, stream, kptr, n, nb, ws, out);
}

// Round 3
// 49.132 us; speedup vs baseline: 1.7771x; 1.7545x over previous
//
#include <hip/hip_runtime.h>

typedef float v2f __attribute__((ext_vector_type(2)));

#define Q_MIN 0.5f
#define S_B_C 1.0f
#define MAXK 512
#define BLK 256
#define GSC 64                    // scatter blocks
#define NCHUNK 4
#define KCHUNK (MAXK / NCHUNK)    // 128
#define MAXB 4096

struct alignas(16) PairRec { v2f c[10]; };  // c[0..7]=2*xa per dim (pair k,k+1), c[8]=u=1-|xa|^2, c[9]=q_ak

struct Scratch {
  unsigned long long blk_packed[GSC][MAXK];  // per-scatter-block argmax tables
  unsigned int blk_fc[GSC][MAXK];            // per-scatter-block segment-max tables
  unsigned int n_bkg;
  unsigned int _pad[3];
  PairRec tabp[MAXK / 2];                    // pair-interleaved center table (80B/pair)
  float fcenterf[MAXK];
  float partial_lv[MAXB];
  float partial_bkg[MAXB];
};

__device__ __forceinline__ float qfun(float fv) {
  float a = atanhf(fv);
  return fmaf(a, a, Q_MIN);
}

__global__ void k_init(Scratch* ws) {
  if (threadIdx.x == 0) ws->n_bkg = 0u;
}

// Phase A: per-block LDS-atomic reduction (no contended global atomics).
// max() is order-independent -> deterministic despite LDS atomic ordering.
__global__ void __launch_bounds__(BLK) k_scatterA(
    const float* __restrict__ f, const int* __restrict__ y,
    const int* __restrict__ ei, const int* __restrict__ ej,
    int n, int e, Scratch* __restrict__ ws) {
  __shared__ unsigned long long sp[MAXK];
  __shared__ unsigned int sf[MAXK];
  for (int t = threadIdx.x; t < MAXK; t += BLK) { sp[t] = 0ull; sf[t] = 0u; }
  __syncthreads();
  int nmax = n > e ? n : e;
  int stride = GSC * BLK;
  for (int t = blockIdx.x * BLK + threadIdx.x; t < nmax; t += stride) {
    if (t < n) {
      int yi = y[t];
      if (yi >= 0 && yi < MAXK) {
        float q = qfun(f[t]);
        unsigned long long p = ((unsigned long long)__float_as_uint(q) << 32)
                             | (unsigned long long)(0xFFFFFFFFu - (unsigned)t);
        atomicMax(&sp[yi], p);
      }
    }
    if (t < e) {
      int j = ej[t];
      if (j >= 0 && j < MAXK)
        atomicMax(&sf[j], __float_as_uint(f[ei[t]]));  // f > 0 so bits-max == fmax
    }
  }
  __syncthreads();
  for (int t = threadIdx.x; t < MAXK; t += BLK) {
    ws->blk_packed[blockIdx.x][t] = sp[t];
    ws->blk_fc[blockIdx.x][t] = sf[t];
  }
}

// Phase B: reduce the GSC block tables (coalesced), build pair-interleaved center table.
__global__ void __launch_bounds__(BLK) k_centers(
    const float* __restrict__ x, int n, Scratch* __restrict__ ws) {
  int t = blockIdx.x * BLK + threadIdx.x;
  if (t >= MAXK) return;
  unsigned long long m = 0ull;
  unsigned int fcb = 0u;
  for (int b = 0; b < GSC; ++b) {
    unsigned long long v = ws->blk_packed[b][t];
    m = v > m ? v : m;
    unsigned int w = ws->blk_fc[b][t];
    fcb = w > fcb ? w : fcb;
  }
  float q = 0.f, u = 0.f;
  float a[8];
  #pragma unroll
  for (int j = 0; j < 8; ++j) a[j] = 0.f;
  if (m != 0ull) {
    q = __uint_as_float((unsigned)(m >> 32));
    unsigned idx = 0xFFFFFFFFu - (unsigned)(m & 0xFFFFFFFFull);
    if (idx < (unsigned)n) {
      const float* xp = x + (size_t)idx * 8;
      float s2 = 0.f;
      #pragma unroll
      for (int j = 0; j < 8; ++j) { float v = xp[j]; s2 = fmaf(v, v, s2); a[j] = 2.f * v; }
      u = 1.f - s2;
    }
  }
  int p = t >> 1, h = t & 1;
  float* rec = (float*)&ws->tabp[p];
  #pragma unroll
  for (int j = 0; j < 8; ++j) rec[2 * j + h] = a[j];
  rec[16 + h] = u;
  rec[18 + h] = q;
  ws->fcenterf[t] = __uint_as_float(fcb);
}

__global__ void __launch_bounds__(BLK) k_main(
    const float* __restrict__ x, const float* __restrict__ f,
    const int* __restrict__ y, int n, int nb_i, Scratch* __restrict__ ws) {
  __shared__ PairRec sTab[KCHUNK / 2];   // 64 * 80B = 5 KB
  int chunk = blockIdx.x / nb_i;
  int iblk  = blockIdx.x - chunk * nb_i;
  int kpair0 = chunk * (KCHUNK / 2);
  {
    const float4* src = (const float4*)&ws->tabp[kpair0];
    float4* dst = (float4*)sTab;
    for (int t = threadIdx.x; t < (KCHUNK / 2) * 5; t += BLK) dst[t] = src[t];
  }
  __syncthreads();

  float lv = 0.f, bk = 0.f;
  int cnt = 0;
  int i = iblk * BLK + threadIdx.x;
  if (i < n) {
    const float4* xp = (const float4*)(x + (size_t)i * 8);
    float4 p0 = xp[0], p1 = xp[1];
    float x2i = p0.x*p0.x + p0.y*p0.y + p0.z*p0.z + p0.w*p0.w
              + p1.x*p1.x + p1.y*p1.y + p1.z*p1.z + p1.w*p1.w;
    int yi = y[i];
    float fi = f[i];
    float qi = qfun(fi);
    v2f dnx2 = { -x2i, -x2i };
    v2f d0x = { p0.x, p0.x }, d0y = { p0.y, p0.y }, d0z = { p0.z, p0.z }, d0w = { p0.w, p0.w };
    v2f d1x = { p1.x, p1.x }, d1y = { p1.y, p1.y }, d1z = { p1.z, p1.z }, d1w = { p1.w, p1.w };
    v2f zero2 = { 0.f, 0.f };
    v2f one2 = { 1.f, 1.f };
    v2f acc2 = zero2;
    #pragma unroll 2
    for (int p = 0; p < KCHUNK / 2; ++p) {
      PairRec rec = sTab[p];                       // 80B broadcast LDS read
      v2f r = rec.c[8] + dnx2;
      r = __builtin_elementwise_fma(d0x, rec.c[0], r);
      r = __builtin_elementwise_fma(d0y, rec.c[1], r);
      r = __builtin_elementwise_fma(d0z, rec.c[2], r);
      r = __builtin_elementwise_fma(d0w, rec.c[3], r);
      r = __builtin_elementwise_fma(d1x, rec.c[4], r);
      r = __builtin_elementwise_fma(d1y, rec.c[5], r);
      r = __builtin_elementwise_fma(d1z, rec.c[6], r);
      r = __builtin_elementwise_fma(d1w, rec.c[7], r);
      v2f xinv = __builtin_elementwise_min(__builtin_elementwise_max(r, zero2), one2);
      acc2 = __builtin_elementwise_fma(xinv, rec.c[9], acc2);
    }
    float acc = acc2[0] + acc2[1];
    int kl = yi - chunk * KCHUNK;
    if (yi >= 0 && kl >= 0 && kl < KCHUNK) {
      // member fixup: replace xinv term for k==yi by x_diff term
      const float* recf = (const float*)&sTab[kl >> 1];
      int h = kl & 1;
      float r = recf[16 + h] - x2i;
      r = fmaf(p0.x, recf[0 + h], r);
      r = fmaf(p0.y, recf[2 + h], r);
      r = fmaf(p0.z, recf[4 + h], r);
      r = fmaf(p0.w, recf[6 + h], r);
      r = fmaf(p1.x, recf[8 + h], r);
      r = fmaf(p1.y, recf[10 + h], r);
      r = fmaf(p1.z, recf[12 + h], r);
      r = fmaf(p1.w, recf[14 + h], r);
      float q = recf[18 + h];
      float xinv = __builtin_amdgcn_fmed3f(r, 0.f, 1.f);
      float xd = fmaxf(1.f - r, 0.f);
      acc += (xd - xinv) * q;
    } else if (yi < 0 && chunk == 0) {
      bk = fi; cnt = 1;
    }
    lv = qi * acc;
  }

  for (int o = 32; o > 0; o >>= 1) {
    lv += __shfl_down(lv, o, 64);
    bk += __shfl_down(bk, o, 64);
    cnt += __shfl_down(cnt, o, 64);
  }
  __shared__ float rlv[BLK / 64], rbk[BLK / 64];
  __shared__ int rcnt[BLK / 64];
  int wid = threadIdx.x >> 6;
  int lane = threadIdx.x & 63;
  if (lane == 0) { rlv[wid] = lv; rbk[wid] = bk; rcnt[wid] = cnt; }
  __syncthreads();
  if (threadIdx.x == 0) {
    float slv = 0.f, sbk = 0.f; int sc = 0;
    #pragma unroll
    for (int w = 0; w < BLK / 64; ++w) { slv += rlv[w]; sbk += rbk[w]; sc += rcnt[w]; }
    ws->partial_lv[blockIdx.x] = slv;
    ws->partial_bkg[blockIdx.x] = sbk;
    if (sc) atomicAdd(&ws->n_bkg, (unsigned)sc);
  }
}

__global__ void __launch_bounds__(BLK) k_final(const int* __restrict__ kptr, int n, int nbt,
    const Scratch* __restrict__ ws, float* __restrict__ out) {
  int K = kptr[0]; if (K > MAXK) K = MAXK;
  int tid = threadIdx.x;
  float a = 0.f, b = 0.f, c = 0.f;
  for (int t = tid; t < nbt; t += BLK) { a += ws->partial_lv[t]; b += ws->partial_bkg[t]; }
  for (int t = tid; t < MAXK; t += BLK) c += ws->fcenterf[t];  // 0 for t >= K
  __shared__ float sa[BLK], sb[BLK], sc[BLK];
  sa[tid] = a; sb[tid] = b; sc[tid] = c;
  __syncthreads();
  for (int o = BLK / 2; o > 0; o >>= 1) {
    if (tid < o) { sa[tid] += sa[tid + o]; sb[tid] += sb[tid + o]; sc[tid] += sc[tid + o]; }
    __syncthreads();
  }
  if (tid == 0) {
    float b1 = 1.f - sc[0] / (float)K;
    float b2 = S_B_C / (float)ws->n_bkg * sb[0];
    out[0] = (b1 + b2) + sa[0] / (float)n;
  }
}

extern "C" void kernel_launch(void* const* d_in, const int* in_sizes, int n_in,
                              void* d_out, int out_size, void* d_ws, size_t ws_size,
                              hipStream_t stream) {
  const float* x = (const float*)d_in[0];
  const float* f = (const float*)d_in[1];
  const int*   y = (const int*)d_in[2];
  const int*  ei = (const int*)d_in[3];
  const int*  ej = (const int*)d_in[4];
  const int* kptr = (const int*)d_in[5];
  float* out = (float*)d_out;
  int n = in_sizes[1];
  int e = in_sizes[3];
  Scratch* ws = (Scratch*)d_ws;

  int nb_i = (n + BLK - 1) / BLK;
  int nbt = nb_i * NCHUNK;
  if (nbt > MAXB) nbt = MAXB;  // n fixed at 100k -> 1564, safe

  hipLaunchKernelGGL(k_init,     dim3(1),              dim3(64),  0, stream, ws);
  hipLaunchKernelGGL(k_scatterA, dim3(GSC),            dim3(BLK), 0, stream, f, y, ei, ej, n, e, ws);
  hipLaunchKernelGGL(k_centers,  dim3(MAXK / BLK),     dim3(BLK), 0, stream, x, n, ws);
  hipLaunchKernelGGL(k_main,     dim3(nbt),            dim3(BLK), 0, stream, x, f, y, n, nb_i, ws);
  hipLaunchKernelGGL(k_final,    dim3(1),              dim3(BLK), 0, stream, kptr, n, nbt, ws, out);
}

// Round 4
// 44.155 us; speedup vs baseline: 1.9775x; 1.1127x over previous
//
#include <hip/hip_runtime.h>

typedef float v2f __attribute__((ext_vector_type(2)));

#define Q_MIN 0.5f
#define S_B_C 1.0f
#define MAXK 512
#define BLK 256
#define GSC 128                   // scatter blocks
#define NCHUNK 8
#define KCHUNK (MAXK / NCHUNK)    // 64
#define KPAIRS (KCHUNK / 2)       // 32
#define HPT 2                     // hits per thread in k_main
#define MAXB 2048

struct alignas(16) PairRec { v2f c[10]; };  // c[0..7]=2*xa[d] (pair k,k+1), c[8]=1-|xa|^2, c[9]=q_ak

struct Scratch {
  unsigned long long blk_packed[GSC][MAXK];  // per-scatter-block argmax tables
  unsigned int blk_fc[GSC][MAXK];            // per-scatter-block segment-max tables
  PairRec tabp[MAXK / 2];                    // pair-interleaved center table
  float fcenterf[MAXK];
  float partial_lv[MAXB];
  float partial_bkg[MAXB];
  float partial_cnt[MAXB];
};

__device__ __forceinline__ float qfun(float fv) {
  float a = atanhf(fv);
  return fmaf(a, a, Q_MIN);
}

// Phase A: per-block LDS-atomic reduction (no contended global atomics).
// max() is order-independent -> deterministic despite LDS atomic ordering.
__global__ void __launch_bounds__(BLK) k_scatterA(
    const float* __restrict__ f, const int* __restrict__ y,
    const int* __restrict__ ei, const int* __restrict__ ej,
    int n, int e, Scratch* __restrict__ ws) {
  __shared__ unsigned long long sp[MAXK];
  __shared__ unsigned int sf[MAXK];
  for (int t = threadIdx.x; t < MAXK; t += BLK) { sp[t] = 0ull; sf[t] = 0u; }
  __syncthreads();
  int nmax = n > e ? n : e;
  int stride = GSC * BLK;
  for (int t = blockIdx.x * BLK + threadIdx.x; t < nmax; t += stride) {
    if (t < n) {
      int yi = y[t];
      if (yi >= 0 && yi < MAXK) {
        float q = qfun(f[t]);
        unsigned long long p = ((unsigned long long)__float_as_uint(q) << 32)
                             | (unsigned long long)(0xFFFFFFFFu - (unsigned)t);
        atomicMax(&sp[yi], p);
      }
    }
    if (t < e) {
      int j = ej[t];
      if (j >= 0 && j < MAXK)
        atomicMax(&sf[j], __float_as_uint(f[ei[t]]));  // f > 0 so bits-max == fmax
    }
  }
  __syncthreads();
  for (int t = threadIdx.x; t < MAXK; t += BLK) {
    ws->blk_packed[blockIdx.x][t] = sp[t];
    ws->blk_fc[blockIdx.x][t] = sf[t];
  }
}

// Phase B: reduce block tables (coalesced), build pair-interleaved center table.
__global__ void __launch_bounds__(BLK) k_centers(
    const float* __restrict__ x, int n, Scratch* __restrict__ ws) {
  int t = blockIdx.x * BLK + threadIdx.x;
  if (t >= MAXK) return;
  unsigned long long m = 0ull;
  unsigned int fcb = 0u;
  for (int b = 0; b < GSC; ++b) {
    unsigned long long v = ws->blk_packed[b][t];
    m = v > m ? v : m;
    unsigned int w = ws->blk_fc[b][t];
    fcb = w > fcb ? w : fcb;
  }
  float q = 0.f, u = 0.f;
  float a[8];
  #pragma unroll
  for (int j = 0; j < 8; ++j) a[j] = 0.f;
  if (m != 0ull) {
    q = __uint_as_float((unsigned)(m >> 32));
    unsigned idx = 0xFFFFFFFFu - (unsigned)(m & 0xFFFFFFFFull);
    if (idx < (unsigned)n) {
      const float* xp = x + (size_t)idx * 8;
      float s2 = 0.f;
      #pragma unroll
      for (int j = 0; j < 8; ++j) { float v = xp[j]; s2 = fmaf(v, v, s2); a[j] = 2.f * v; }
      u = 1.f - s2;
    }
  }
  int p = t >> 1, h = t & 1;
  float* rec = (float*)&ws->tabp[p];
  #pragma unroll
  for (int j = 0; j < 8; ++j) rec[2 * j + h] = a[j];
  rec[16 + h] = u;
  rec[18 + h] = q;
  ws->fcenterf[t] = __uint_as_float(fcb);
}

__global__ void __launch_bounds__(BLK) k_main(
    const float* __restrict__ x, const float* __restrict__ f,
    const int* __restrict__ y, int n, int nb_i, Scratch* __restrict__ ws) {
  __shared__ PairRec sTab[KPAIRS];   // 32 * 80B = 2.5 KB
  int chunk = blockIdx.x / nb_i;
  int iblk  = blockIdx.x - chunk * nb_i;
  {
    const float4* src = (const float4*)&ws->tabp[chunk * KPAIRS];
    float4* dst = (float4*)sTab;
    for (int t = threadIdx.x; t < KPAIRS * 5; t += BLK) dst[t] = src[t];
  }
  __syncthreads();

  int k0 = chunk * KCHUNK;
  int base = iblk * (BLK * HPT) + threadIdx.x;

  float4 p0[HPT], p1[HPT];
  float x2[HPT], fi[HPT], qi[HPT];
  int yi[HPT];
  v2f acc2[HPT];
  #pragma unroll
  for (int h = 0; h < HPT; ++h) {
    int i = base + h * BLK;
    bool v = (i < n);
    int ic = v ? i : 0;
    const float4* xp = (const float4*)(x + (size_t)ic * 8);
    p0[h] = xp[0]; p1[h] = xp[1];
    fi[h] = f[ic];
    yi[h] = v ? y[ic] : -2;          // -2: neither member nor background
    qi[h] = v ? qfun(fi[h]) : 0.f;   // 0 kills invalid-lane contribution
    x2[h] = p0[h].x*p0[h].x + p0[h].y*p0[h].y + p0[h].z*p0[h].z + p0[h].w*p0[h].w
          + p1[h].x*p1[h].x + p1[h].y*p1[h].y + p1[h].z*p1[h].z + p1[h].w*p1[h].w;
    acc2[h] = (v2f){0.f, 0.f};
  }

  v2f zero2 = { 0.f, 0.f };
  v2f one2 = { 1.f, 1.f };
  #pragma unroll 2
  for (int p = 0; p < KPAIRS; ++p) {
    PairRec rec = sTab[p];           // wave-uniform broadcast LDS read
    #pragma unroll
    for (int h = 0; h < HPT; ++h) {
      v2f r = rec.c[8] + (v2f){-x2[h], -x2[h]};
      r = __builtin_elementwise_fma((v2f){p0[h].x, p0[h].x}, rec.c[0], r);
      r = __builtin_elementwise_fma((v2f){p0[h].y, p0[h].y}, rec.c[1], r);
      r = __builtin_elementwise_fma((v2f){p0[h].z, p0[h].z}, rec.c[2], r);
      r = __builtin_elementwise_fma((v2f){p0[h].w, p0[h].w}, rec.c[3], r);
      r = __builtin_elementwise_fma((v2f){p1[h].x, p1[h].x}, rec.c[4], r);
      r = __builtin_elementwise_fma((v2f){p1[h].y, p1[h].y}, rec.c[5], r);
      r = __builtin_elementwise_fma((v2f){p1[h].z, p1[h].z}, rec.c[6], r);
      r = __builtin_elementwise_fma((v2f){p1[h].w, p1[h].w}, rec.c[7], r);
      v2f xinv = __builtin_elementwise_min(__builtin_elementwise_max(r, zero2), one2);
      acc2[h] = __builtin_elementwise_fma(xinv, rec.c[9], acc2[h]);
    }
  }

  float lv = 0.f, bk = 0.f, ct = 0.f;
  #pragma unroll
  for (int h = 0; h < HPT; ++h) {
    float acc = acc2[h][0] + acc2[h][1];
    int kl = yi[h] - k0;
    if (yi[h] >= 0 && kl >= 0 && kl < KCHUNK) {
      // member fixup: replace xinv term for k==yi by x_diff term
      const float* recf = (const float*)&sTab[kl >> 1];
      int hh = kl & 1;
      float r = recf[16 + hh] - x2[h];
      r = fmaf(p0[h].x, recf[0 + hh], r);
      r = fmaf(p0[h].y, recf[2 + hh], r);
      r = fmaf(p0[h].z, recf[4 + hh], r);
      r = fmaf(p0[h].w, recf[6 + hh], r);
      r = fmaf(p1[h].x, recf[8 + hh], r);
      r = fmaf(p1[h].y, recf[10 + hh], r);
      r = fmaf(p1[h].z, recf[12 + hh], r);
      r = fmaf(p1[h].w, recf[14 + hh], r);
      float qk = recf[18 + hh];
      float xinv = __builtin_amdgcn_fmed3f(r, 0.f, 1.f);
      float xd = fmaxf(1.f - r, 0.f);
      acc += (xd - xinv) * qk;
    } else if (yi[h] == -1 && chunk == 0) {
      bk += fi[h]; ct += 1.f;
    }
    lv = fmaf(qi[h], acc, lv);
  }

  for (int o = 32; o > 0; o >>= 1) {
    lv += __shfl_down(lv, o, 64);
    bk += __shfl_down(bk, o, 64);
    ct += __shfl_down(ct, o, 64);
  }
  __shared__ float rlv[BLK / 64], rbk[BLK / 64], rct[BLK / 64];
  int wid = threadIdx.x >> 6;
  int lane = threadIdx.x & 63;
  if (lane == 0) { rlv[wid] = lv; rbk[wid] = bk; rct[wid] = ct; }
  __syncthreads();
  if (threadIdx.x == 0) {
    float slv = 0.f, sbk = 0.f, sct = 0.f;
    #pragma unroll
    for (int w = 0; w < BLK / 64; ++w) { slv += rlv[w]; sbk += rbk[w]; sct += rct[w]; }
    ws->partial_lv[blockIdx.x] = slv;
    ws->partial_bkg[blockIdx.x] = sbk;
    ws->partial_cnt[blockIdx.x] = sct;
  }
}

__global__ void __launch_bounds__(BLK) k_final(const int* __restrict__ kptr, int n, int nbt,
    const Scratch* __restrict__ ws, float* __restrict__ out) {
  int K = kptr[0]; if (K > MAXK) K = MAXK;
  int tid = threadIdx.x;
  float a = 0.f, b = 0.f, c = 0.f, d = 0.f;
  for (int t = tid; t < nbt; t += BLK) {
    a += ws->partial_lv[t]; b += ws->partial_bkg[t]; c += ws->partial_cnt[t];
  }
  for (int t = tid; t < MAXK; t += BLK) d += ws->fcenterf[t];  // 0 for t >= K
  __shared__ float sa[BLK], sb[BLK], sc[BLK], sd[BLK];
  sa[tid] = a; sb[tid] = b; sc[tid] = c; sd[tid] = d;
  __syncthreads();
  for (int o = BLK / 2; o > 0; o >>= 1) {
    if (tid < o) {
      sa[tid] += sa[tid + o]; sb[tid] += sb[tid + o];
      sc[tid] += sc[tid + o]; sd[tid] += sd[tid + o];
    }
    __syncthreads();
  }
  if (tid == 0) {
    float b1 = 1.f - sd[0] / (float)K;
    float b2 = S_B_C / sc[0] * sb[0];   // sc = n_bkg (exact integer-valued float)
    out[0] = (b1 + b2) + sa[0] / (float)n;
  }
}

extern "C" void kernel_launch(void* const* d_in, const int* in_sizes, int n_in,
                              void* d_out, int out_size, void* d_ws, size_t ws_size,
                              hipStream_t stream) {
  const float* x = (const float*)d_in[0];
  const float* f = (const float*)d_in[1];
  const int*   y = (const int*)d_in[2];
  const int*  ei = (const int*)d_in[3];
  const int*  ej = (const int*)d_in[4];
  const int* kptr = (const int*)d_in[5];
  float* out = (float*)d_out;
  int n = in_sizes[1];
  int e = in_sizes[3];
  Scratch* ws = (Scratch*)d_ws;

  int nb_i = (n + BLK * HPT - 1) / (BLK * HPT);
  int nbt = nb_i * NCHUNK;
  if (nbt > MAXB) nbt = MAXB;  // n=100k -> 1568, safe

  hipLaunchKernelGGL(k_scatterA, dim3(GSC),        dim3(BLK), 0, stream, f, y, ei, ej, n, e, ws);
  hipLaunchKernelGGL(k_centers,  dim3(MAXK / BLK), dim3(BLK), 0, stream, x, n, ws);
  hipLaunchKernelGGL(k_main,     dim3(nbt),        dim3(BLK), 0, stream, x, f, y, n, nb_i, ws);
  hipLaunchKernelGGL(k_final,    dim3(1),          dim3(BLK), 0, stream, kptr, n, nbt, ws, out);
}